// Round 2
// baseline (10408.010 us; speedup 1.0000x reference)
//
#include <hip/hip_runtime.h>

// SLAYER SRM-alpha constants, computed in f64 then cast to f32 to match
// Python: A = exp(-0.1); c1 = f32(2A); c2 = f32(A*A); c3 = f32(e*A/10).
__device__ constexpr float C1f = (float)1.80967483607191914632;   // 2*exp(-0.1)
__device__ constexpr float C2f = (float)0.81873075307798185867;   // exp(-0.2)
__device__ constexpr float C3f = (float)0.24596031111569496638;   // e^0.9/10

// One fused time-step: psp IIR (input acc), refractory IIR (input past spike),
// threshold. Literal (non-contracted) arithmetic to match the JAX scan.
__device__ __forceinline__ float iir_spike_step(float acc, float& y1, float& y2, float& xp,
                                                float& r1, float& r2, float& sp) {
#pragma clang fp contract(off)
    float u = C1f * y1 - C2f * y2 + C3f * xp;   // psp output at t (uses x[t-1])
    float r = C1f * r1 - C2f * r2 + C3f * sp;   // alpha response to past spikes
    float s = (u - 20.0f * r >= 10.0f) ? 1.0f : 0.0f;
    y2 = y1; y1 = u; xp = acc;
    r2 = r1; r1 = r; sp = s;
    return s;
}

// K0: pool s_in [B,2,128,128,T] f32 -> counts u8 [T][B][2][64][64]
__global__ void k_pool0(const float* __restrict__ s_in, unsigned char* __restrict__ out) {
    int idx = blockIdx.x * 256 + threadIdx.x;          // [t][b][c][ho][wo]
    if (idx >= 100 * 4 * 2 * 64 * 64) return;
    int wo = idx & 63;
    int ho = (idx >> 6) & 63;
    int c  = (idx >> 12) & 1;
    int b  = (idx >> 13) & 3;
    int t  = idx >> 15;
    const float* p = s_in + ((size_t)(((b * 2 + c) * 128 + ho * 2) * 128 + wo * 2)) * 100 + t;
    int cnt = (p[0] > 0.5f) + (p[100] > 0.5f) + (p[12800] > 0.5f) + (p[12900] > 0.5f);
    out[idx] = (unsigned char)cnt;
}

// K1: psp+spike over pooled counts (x = 11*count). in/out planes [T][nloc]
__global__ void k_psp_spike_pool(const unsigned char* __restrict__ in,
                                 unsigned char* __restrict__ out, int nloc) {
    int loc = blockIdx.x * 256 + threadIdx.x;
    if (loc >= nloc) return;
    float y1 = 0, y2 = 0, xp = 0, r1 = 0, r2 = 0, sp = 0;
    for (int t = 0; t < 100; ++t) {
        float acc = 11.0f * (float)in[t * nloc + loc];
        float s = iir_spike_step(acc, y1, y2, xp, r1, r2, sp);
        out[t * nloc + loc] = (unsigned char)s;
    }
}

// Fused 2x2 sum-pool (x11) + psp + spike. in [T][BC][Hi][Wi] u8 -> out [T][BC][Hi/2][Wi/2] u8
__global__ void k_pool_psp_spike(const unsigned char* __restrict__ in,
                                 unsigned char* __restrict__ out,
                                 int BC, int Hi, int Wi) {
    int Ho = Hi >> 1, Wo = Wi >> 1;
    int nloc_o = BC * Ho * Wo;
    int nloc_i = BC * Hi * Wi;
    int loc = blockIdx.x * 256 + threadIdx.x;
    if (loc >= nloc_o) return;
    int wo = loc % Wo;
    int t1 = loc / Wo;
    int ho = t1 % Ho;
    int bc = t1 / Ho;
    const unsigned char* ip = in + (bc * Hi + ho * 2) * Wi + wo * 2;
    float y1 = 0, y2 = 0, xp = 0, r1 = 0, r2 = 0, sp = 0;
    for (int t = 0; t < 100; ++t) {
        int cnt = ip[0] + ip[1] + ip[Wi] + ip[Wi + 1];
        float s = iir_spike_step(11.0f * (float)cnt, y1, y2, xp, r1, r2, sp);
        out[t * nloc_o + loc] = (unsigned char)s;
        ip += nloc_i;
    }
}

// Fused conv(KSxKS, pad) + psp + spike. One thread per (b,o,h,w), t-loop inside.
// in [T][B][CIN][H][W] u8, wt [O][CIN][KS][KS] f32, out [T][B][O][H][W] u8.
// Block = 256 threads, uniform (b,o) per block (H*W is a multiple of 256).
template <int CIN, int KS, int PAD, int H, int W>
__global__ void k_conv_psp_spike(const unsigned char* __restrict__ in,
                                 const float* __restrict__ wt,
                                 unsigned char* __restrict__ out,
                                 int B, int O) {
    int idx = blockIdx.x * 256 + threadIdx.x;
    int w = idx % W;
    int h = (idx / W) % H;
    int o = (idx / (W * H)) % O;
    int b = idx / (W * H * O);

    __shared__ float wsm[CIN * KS * KS];
    for (int i = threadIdx.x; i < CIN * KS * KS; i += 256)
        wsm[i] = wt[o * CIN * KS * KS + i];
    __syncthreads();

    int plane_i = B * CIN * H * W;
    int plane_o = B * O * H * W;
    int oidx = ((b * O + o) * H + h) * W + w;

    const unsigned char* base = in + (b * CIN) * H * W;
    float y1 = 0, y2 = 0, xp = 0, r1 = 0, r2 = 0, sp = 0;
    for (int t = 0; t < 100; ++t) {
        float acc = 0.0f;
        const unsigned char* pc = base;
        for (int c = 0; c < CIN; ++c) {
#pragma unroll
            for (int kh = 0; kh < KS; ++kh) {
                int ih = h - PAD + kh;
                if (ih >= 0 && ih < H) {
#pragma unroll
                    for (int kw = 0; kw < KS; ++kw) {
                        int iw = w - PAD + kw;
                        if (iw >= 0 && iw < W)
                            acc += (float)pc[ih * W + iw] * wsm[(c * KS + kh) * KS + kw];
                    }
                }
            }
            pc += H * W;
        }
        float s = iir_spike_step(acc, y1, y2, xp, r1, r2, sp);
        out[t * plane_o + oidx] = (unsigned char)s;
        base += plane_i;
    }
}

// K8: dense 8192->512 fused. One wave per (b,o). in [T][B][8192] u8, wt [512][8192].
__global__ void k_dense4a(const unsigned char* __restrict__ in,
                          const float* __restrict__ wt,
                          unsigned char* __restrict__ out) {
    int wid = (blockIdx.x * 256 + threadIdx.x) >> 6;
    int lane = threadIdx.x & 63;
    int o = wid & 511;
    int b = wid >> 9;

    // interleaved weight preload: element f = (j*64 + lane)*4 + k  (coalesced float4)
    float4 wv[32];
    const float4* wp = (const float4*)(wt + (size_t)o * 8192);
#pragma unroll
    for (int j = 0; j < 32; ++j) wv[j] = wp[j * 64 + lane];

    float y1 = 0, y2 = 0, xp = 0, r1 = 0, r2 = 0, sp = 0;
    for (int t = 0; t < 100; ++t) {
        const uchar4* ip = (const uchar4*)(in + (size_t)(t * 4 + b) * 8192);
        float acc = 0.0f;
#pragma unroll
        for (int j = 0; j < 32; ++j) {
            uchar4 v = ip[j * 64 + lane];
            acc += wv[j].x * (float)v.x + wv[j].y * (float)v.y +
                   wv[j].z * (float)v.z + wv[j].w * (float)v.w;
        }
#pragma unroll
        for (int off = 32; off > 0; off >>= 1) acc += __shfl_xor(acc, off, 64);
        float s = iir_spike_step(acc, y1, y2, xp, r1, r2, sp);
        if (lane == 0) out[t * 2048 + b * 512 + o] = (unsigned char)s;
    }
}

// K9: dense 512->11 fused, writes final output [B][11][T] f32.
__global__ void k_dense4b(const unsigned char* __restrict__ in,
                          const float* __restrict__ wt,
                          float* __restrict__ out) {
    int wid = blockIdx.x;     // 44 waves: one per (b,o)
    int lane = threadIdx.x;
    int o = wid % 11;
    int b = wid / 11;

    float wreg[8];
    const float* wp = wt + o * 512 + lane * 8;
#pragma unroll
    for (int k = 0; k < 8; ++k) wreg[k] = wp[k];

    float y1 = 0, y2 = 0, xp = 0, r1 = 0, r2 = 0, sp = 0;
    for (int t = 0; t < 100; ++t) {
        const unsigned char* ip = in + (size_t)(t * 4 + b) * 512 + lane * 8;
        uchar4 a = *(const uchar4*)ip;
        uchar4 c = *(const uchar4*)(ip + 4);
        float acc = wreg[0] * (float)a.x + wreg[1] * (float)a.y +
                    wreg[2] * (float)a.z + wreg[3] * (float)a.w +
                    wreg[4] * (float)c.x + wreg[5] * (float)c.y +
                    wreg[6] * (float)c.z + wreg[7] * (float)c.w;
#pragma unroll
        for (int off = 32; off > 0; off >>= 1) acc += __shfl_xor(acc, off, 64);
        float s = iir_spike_step(acc, y1, y2, xp, r1, r2, sp);
        if (lane == 0) out[(b * 11 + o) * 100 + t] = s;
    }
}

extern "C" void kernel_launch(void* const* d_in, const int* in_sizes, int n_in,
                              void* d_out, int out_size, void* d_ws, size_t ws_size,
                              hipStream_t stream) {
    const float* s_in = (const float*)d_in[0];
    const float* w1   = (const float*)d_in[1];
    const float* w2   = (const float*)d_in[2];
    const float* w3   = (const float*)d_in[3];
    const float* w4a  = (const float*)d_in[4];
    const float* w4b  = (const float*)d_in[5];
    float* out = (float*)d_out;

    // ping-pong workspace regions: A = 52,428,800 B, B = 13,107,200 B
    unsigned char* A  = (unsigned char*)d_ws;
    unsigned char* Bb = A + 52428800;

    // SP0: pool + psp + spike
    k_pool0<<<12800, 256, 0, stream>>>(s_in, A);                        // A = pool counts [T][32768]
    k_psp_spike_pool<<<128, 256, 0, stream>>>(A, Bb, 32768);            // B = spikes0

    // SC1: conv 5x5 pad2 (2->32) + psp + spike
    k_conv_psp_spike<2, 5, 2, 64, 64><<<2048, 256, 0, stream>>>(Bb, w1, A, 4, 32);   // A = spikes1

    // SP1
    k_pool_psp_spike<<<512, 256, 0, stream>>>(A, Bb, 128, 64, 64);      // B = spikes2

    // SC2: conv 3x3 pad1 (32->64)
    k_conv_psp_spike<32, 3, 1, 32, 32><<<1024, 256, 0, stream>>>(Bb, w2, A, 4, 64);  // A = spikes3

    // SP2
    k_pool_psp_spike<<<256, 256, 0, stream>>>(A, Bb, 256, 32, 32);      // B = spikes4

    // SC3: conv 3x3 pad1 (64->128)
    k_conv_psp_spike<64, 3, 1, 16, 16><<<512, 256, 0, stream>>>(Bb, w3, A, 4, 128);  // A = spikes5

    // SP3
    k_pool_psp_spike<<<128, 256, 0, stream>>>(A, Bb, 512, 16, 16);      // B = spikes6

    // SF4a: dense 8192->512
    k_dense4a<<<512, 256, 0, stream>>>(Bb, w4a, A);                     // A = spikes7 [T][B][512]

    // SF4b: dense 512->11 -> final output [B][11][T]
    k_dense4b<<<44, 64, 0, stream>>>(A, w4b, out);
}

// Round 4
// 2633.958 us; speedup vs baseline: 3.9515x; 3.9515x over previous
//
#include <hip/hip_runtime.h>

// SLAYER SRM-alpha constants (f64-computed, f32-cast):
__device__ constexpr float C1f = (float)1.80967483607191914632;   // 2*exp(-0.1)
__device__ constexpr float C2f = (float)0.81873075307798185867;   // exp(-0.2)
__device__ constexpr float C3f = (float)0.24596031111569496638;   // e^0.9/10

__device__ __forceinline__ float iir_spike_step(float acc, float& y1, float& y2, float& xp,
                                                float& r1, float& r2, float& sp) {
#pragma clang fp contract(off)
    float u = C1f * y1 - C2f * y2 + C3f * xp;   // psp output at t (uses x[t-1])
    float r = C1f * r1 - C2f * r2 + C3f * sp;   // alpha response to past spikes
    float s = (u - 20.0f * r >= 10.0f) ? 1.0f : 0.0f;
    y2 = y1; y1 = u; xp = acc;
    r2 = r1; r1 = r; sp = s;
    return s;
}

// ---------------- SP0: pool(2x2 of s_in) + psp + spike -> w-packed row masks
// s0m layout: [t][b][c][h] ulong (bit w). Wave = one row (b,c,h), lane = w.
__global__ void k_sp0(const float* __restrict__ s_in, unsigned long long* __restrict__ s0m) {
    int wid = (blockIdx.x * 256 + threadIdx.x) >> 6;   // 0..511 = (b,c,h)
    int lane = threadIdx.x & 63;                        // w
    int h = wid & 63;
    int c = (wid >> 6) & 1;
    int b = wid >> 7;
    const float* p00 = s_in + ((size_t)(((b * 2 + c) * 128 + 2 * h) * 128 + 2 * lane)) * 100;
    const float* p01 = p00 + 100;
    const float* p10 = p00 + 12800;
    const float* p11 = p10 + 100;
    float y1 = 0, y2 = 0, xp = 0, r1 = 0, r2 = 0, sp = 0;
    for (int t = 0; t < 100; ++t) {
        float cnt = (p00[t] > 0.5f) + (p01[t] > 0.5f) + (p10[t] > 0.5f) + (p11[t] > 0.5f);
        float s = iir_spike_step(11.0f * cnt, y1, y2, xp, r1, r2, sp);
        unsigned long long m = __ballot(s > 0.5f);
        if (lane == 0) s0m[((size_t)(t * 4 + b) * 2 + c) * 64 + h] = m;
    }
}

// ---------------- SC1: 5x5 conv (2ch) via row-mask per-bit iteration (order-exact
// vs dense (c,kh,kw) loop) + psp + spike -> s1m row masks [t][b][o][h] ulong (bit w).
__global__ void k_sc1(const unsigned long long* __restrict__ s0m, const float* __restrict__ w1,
                      unsigned long long* __restrict__ s1m) {
    int hg = blockIdx.x & 15;
    int o  = (blockIdx.x >> 4) & 31;
    int b  = blockIdx.x >> 9;
    __shared__ float wsm[50];               // [c*25 + kh*5 + kw]
    for (int i = threadIdx.x; i < 50; i += 256) wsm[i] = w1[o * 50 + i];
    __syncthreads();
    int h = hg * 4 + (threadIdx.x >> 6);
    int lane = threadIdx.x & 63;            // w
    int sh = lane - 2;
    float y1 = 0, y2 = 0, xp = 0, r1 = 0, r2 = 0, sp = 0;
    for (int t = 0; t < 100; ++t) {
        float acc = 0.0f;
        const unsigned long long* rb = s0m + (size_t)(t * 4 + b) * 128;
#pragma unroll
        for (int c = 0; c < 2; ++c) {
#pragma unroll
            for (int kh = 0; kh < 5; ++kh) {
                int ih = h - 2 + kh;
                unsigned long long m = (ih >= 0 && ih < 64) ? rb[c * 64 + ih] : 0ULL;
                unsigned pat = (sh >= 0) ? ((unsigned)(m >> sh) & 31u)
                                         : (((unsigned)m << (-sh)) & 31u);
                while (pat) {                       // ascending kw: bit-exact vs dense loop
                    int j = __builtin_ctz(pat);
                    pat &= pat - 1;
                    acc += wsm[c * 25 + kh * 5 + j];
                }
            }
        }
        float s = iir_spike_step(acc, y1, y2, xp, r1, r2, sp);
        unsigned long long mm = __ballot(s > 0.5f);
        if (lane == 0) s1m[((size_t)(t * 4 + b) * 32 + o) * 64 + h] = mm;
    }
}

// ---------------- SP1: pool SC1 spikes -> c-packed masks s2m [t][b][32][32] uint (bit c)
// Wave: (b,ho,wo-pair); lane = c(0..31) + 32*q, q = which wo of the pair.
__global__ void k_sp1(const unsigned long long* __restrict__ s1m, unsigned* __restrict__ s2m) {
    int wid = (blockIdx.x * 256 + threadIdx.x) >> 6;   // (b*32+ho)*16+wop
    int lane = threadIdx.x & 63;
    int wop = wid & 15;
    int ho = (wid >> 4) & 31;
    int b = wid >> 9;
    int c = lane & 31;
    int q = lane >> 5;
    int w = wop * 2 + q;                                // output wo
    float y1 = 0, y2 = 0, xp = 0, r1 = 0, r2 = 0, sp = 0;
    for (int t = 0; t < 100; ++t) {
        const unsigned long long* base = s1m + ((size_t)(t * 4 + b) * 32 + c) * 64 + 2 * ho;
        unsigned long long m0 = base[0], m1 = base[1];
        unsigned v0 = (unsigned)(m0 >> (2 * w)) & 3u;
        unsigned v1 = (unsigned)(m1 >> (2 * w)) & 3u;
        float cnt = (float)((v0 & 1) + (v0 >> 1) + (v1 & 1) + (v1 >> 1));
        float s = iir_spike_step(11.0f * cnt, y1, y2, xp, r1, r2, sp);
        unsigned long long mm = __ballot(s > 0.5f);
        if (lane == 0)  s2m[((size_t)(t * 4 + b) * 32 + ho) * 32 + wop * 2]     = (unsigned)mm;
        if (lane == 32) s2m[((size_t)(t * 4 + b) * 32 + ho) * 32 + wop * 2 + 1] = (unsigned)(mm >> 32);
    }
}

// ---------------- weight transposes into ws: wT[pos][c][o]
__global__ void k_wT(const float* __restrict__ w2, const float* __restrict__ w3,
                     float* __restrict__ w2T, float* __restrict__ w3T) {
    int i = blockIdx.x * 256 + threadIdx.x;
    if (i < 9 * 32 * 64) {
        int o = i & 63; int c = (i >> 6) & 31; int p = i >> 11;
        w2T[i] = w2[(o * 32 + c) * 9 + p];
    }
    if (i < 9 * 64 * 128) {
        int o = i & 127; int c = (i >> 7) & 63; int p = i >> 13;
        w3T[i] = w3[(o * 64 + c) * 9 + p];
    }
}

// ---------------- SC2: sparse 3x3 conv (32c -> 64o) + psp + spike -> sc2m ulong (bit o)
// Wave = 64 o's of one pixel; mask wave-uniform, scalar ctz loop. LDS [9*32][64] = 72KB.
__global__ void k_sc2(const unsigned* __restrict__ s2m, const float* __restrict__ w2T,
                      unsigned long long* __restrict__ sc2m) {
    extern __shared__ float wl[];
    for (int i = threadIdx.x; i < 9 * 32 * 64; i += 256) wl[i] = w2T[i];
    __syncthreads();
    int pg = blockIdx.x & 255;
    int b = blockIdx.x >> 8;
    int pix = pg * 4 + (threadIdx.x >> 6);
    int h = pix >> 5, w = pix & 31;
    int lane = threadIdx.x & 63;   // o
    float y1 = 0, y2 = 0, xp = 0, r1 = 0, r2 = 0, sp = 0;
    for (int t = 0; t < 100; ++t) {
        const unsigned* mb = s2m + (size_t)(t * 4 + b) * 1024;
        float acc = 0.0f;
#pragma unroll
        for (int kh = 0; kh < 3; ++kh) {
            int ih = h - 1 + kh;
            if (ih < 0 || ih >= 32) continue;
#pragma unroll
            for (int kw = 0; kw < 3; ++kw) {
                int iw = w - 1 + kw;
                if (iw < 0 || iw >= 32) continue;
                unsigned m = __builtin_amdgcn_readfirstlane(mb[ih * 32 + iw]);
                int pbase = (kh * 3 + kw) * 32 * 64;
                while (m) {
                    int c = __builtin_ctz(m);
                    m &= m - 1;
                    acc += wl[pbase + c * 64 + lane];
                }
            }
        }
        float s = iir_spike_step(acc, y1, y2, xp, r1, r2, sp);
        unsigned long long mm = __ballot(s > 0.5f);
        if (lane == 0) sc2m[(size_t)(t * 4 + b) * 1024 + pix] = mm;
    }
}

// ---------------- SP2: pool SC2 masks -> s3m [t][b][16][16] ulong (bit c of 64)
__global__ void k_sp2(const unsigned long long* __restrict__ sc2m,
                      unsigned long long* __restrict__ s3m) {
    int wid = (blockIdx.x * 256 + threadIdx.x) >> 6;   // (b*16+ho)*16+wo
    int lane = threadIdx.x & 63;                        // c
    int wo = wid & 15;
    int ho = (wid >> 4) & 15;
    int b = wid >> 8;
    float y1 = 0, y2 = 0, xp = 0, r1 = 0, r2 = 0, sp = 0;
    for (int t = 0; t < 100; ++t) {
        const unsigned long long* mb = sc2m + (size_t)(t * 4 + b) * 1024 + (2 * ho) * 32 + 2 * wo;
        unsigned long long a0 = mb[0], a1 = mb[1], a2 = mb[32], a3 = mb[33];
        float cnt = (float)(((a0 >> lane) & 1) + ((a1 >> lane) & 1) +
                            ((a2 >> lane) & 1) + ((a3 >> lane) & 1));
        float s = iir_spike_step(11.0f * cnt, y1, y2, xp, r1, r2, sp);
        unsigned long long mm = __ballot(s > 0.5f);
        if (lane == 0) s3m[(size_t)(t * 4 + b) * 256 + ho * 16 + wo] = mm;
    }
}

// ---------------- SC3: sparse 3x3 conv (64c -> 128o, o-half per block) -> s4m [..][pix][2] ulong
// LDS [9*64][64] = 144KB dynamic.
__global__ void k_sc3(const unsigned long long* __restrict__ s3m, const float* __restrict__ w3T,
                      unsigned long long* __restrict__ s4m) {
    extern __shared__ float wl[];
    int half = blockIdx.x & 1;
    int pg = (blockIdx.x >> 1) & 63;
    int b = blockIdx.x >> 7;
    for (int i = threadIdx.x; i < 9 * 64 * 64; i += 256) {
        int o = i & 63; int pc = i >> 6;               // pc = p*64+c
        wl[i] = w3T[pc * 128 + half * 64 + o];
    }
    __syncthreads();
    int pix = pg * 4 + (threadIdx.x >> 6);
    int h = pix >> 4, w = pix & 15;
    int lane = threadIdx.x & 63;   // o within half
    float y1 = 0, y2 = 0, xp = 0, r1 = 0, r2 = 0, sp = 0;
    for (int t = 0; t < 100; ++t) {
        const unsigned long long* mb = s3m + (size_t)(t * 4 + b) * 256;
        float acc = 0.0f;
#pragma unroll
        for (int kh = 0; kh < 3; ++kh) {
            int ih = h - 1 + kh;
            if (ih < 0 || ih >= 16) continue;
#pragma unroll
            for (int kw = 0; kw < 3; ++kw) {
                int iw = w - 1 + kw;
                if (iw < 0 || iw >= 16) continue;
                unsigned long long mm64 = mb[ih * 16 + iw];
                unsigned lo = __builtin_amdgcn_readfirstlane((unsigned)mm64);
                unsigned hi = __builtin_amdgcn_readfirstlane((unsigned)(mm64 >> 32));
                int pbase = (kh * 3 + kw) * 64 * 64;
                while (lo) {
                    int c = __builtin_ctz(lo);
                    lo &= lo - 1;
                    acc += wl[pbase + c * 64 + lane];
                }
                while (hi) {
                    int c = 32 + __builtin_ctz(hi);
                    hi &= hi - 1;
                    acc += wl[pbase + c * 64 + lane];
                }
            }
        }
        float s = iir_spike_step(acc, y1, y2, xp, r1, r2, sp);
        unsigned long long mm = __ballot(s > 0.5f);
        if (lane == 0) s4m[((size_t)(t * 4 + b) * 256 + pix) * 2 + half] = mm;
    }
}

// ---------------- SP3: pool SC3 masks -> u8 spikes s5 [t][b][c=128][pix=64] (= [t][b][8192])
// Wave = (b,c); lane = output pixel (8x8). Pixel stride = 2 ulongs!
__global__ void k_sp3(const unsigned long long* __restrict__ s4m, unsigned char* __restrict__ s5) {
    int wid = (blockIdx.x * 256 + threadIdx.x) >> 6;   // b*128 + c
    int lane = threadIdx.x & 63;
    int c = wid & 127;
    int b = wid >> 7;
    int half = c >> 6;
    int cbit = c & 63;
    int ho = lane >> 3, wo = lane & 7;
    float y1 = 0, y2 = 0, xp = 0, r1 = 0, r2 = 0, sp = 0;
    for (int t = 0; t < 100; ++t) {
        const unsigned long long* mb =
            s4m + ((size_t)(t * 4 + b) * 256 + (2 * ho) * 16 + 2 * wo) * 2 + half;
        // input pixels: (2ho,2wo)=+0, (2ho,2wo+1)=+2, (2ho+1,2wo)=+32, (2ho+1,2wo+1)=+34
        unsigned long long a0 = mb[0], a1 = mb[2], a2 = mb[32], a3 = mb[34];
        float cnt = (float)(((a0 >> cbit) & 1) + ((a1 >> cbit) & 1) +
                            ((a2 >> cbit) & 1) + ((a3 >> cbit) & 1));
        float s = iir_spike_step(11.0f * cnt, y1, y2, xp, r1, r2, sp);
        s5[((size_t)(t * 4 + b) * 128 + c) * 64 + lane] = (unsigned char)s;
    }
}

// ---------------- SF4a: dense 8192->512 fused
__global__ void k_dense4a(const unsigned char* __restrict__ in,
                          const float* __restrict__ wt,
                          unsigned char* __restrict__ out) {
    int wid = (blockIdx.x * 256 + threadIdx.x) >> 6;
    int lane = threadIdx.x & 63;
    int o = wid & 511;
    int b = wid >> 9;
    float4 wv[32];
    const float4* wp = (const float4*)(wt + (size_t)o * 8192);
#pragma unroll
    for (int j = 0; j < 32; ++j) wv[j] = wp[j * 64 + lane];
    float y1 = 0, y2 = 0, xp = 0, r1 = 0, r2 = 0, sp = 0;
    for (int t = 0; t < 100; ++t) {
        const uchar4* ip = (const uchar4*)(in + (size_t)(t * 4 + b) * 8192);
        float acc = 0.0f;
#pragma unroll
        for (int j = 0; j < 32; ++j) {
            uchar4 v = ip[j * 64 + lane];
            acc += wv[j].x * (float)v.x + wv[j].y * (float)v.y +
                   wv[j].z * (float)v.z + wv[j].w * (float)v.w;
        }
#pragma unroll
        for (int off = 32; off > 0; off >>= 1) acc += __shfl_xor(acc, off, 64);
        float s = iir_spike_step(acc, y1, y2, xp, r1, r2, sp);
        if (lane == 0) out[t * 2048 + b * 512 + o] = (unsigned char)s;
    }
}

// ---------------- SF4b: dense 512->11 -> final out [B][11][T] f32
__global__ void k_dense4b(const unsigned char* __restrict__ in,
                          const float* __restrict__ wt,
                          float* __restrict__ out) {
    int wid = blockIdx.x;      // 44 = (b,o)
    int lane = threadIdx.x;
    int o = wid % 11;
    int b = wid / 11;
    float wreg[8];
    const float* wp = wt + o * 512 + lane * 8;
#pragma unroll
    for (int k = 0; k < 8; ++k) wreg[k] = wp[k];
    float y1 = 0, y2 = 0, xp = 0, r1 = 0, r2 = 0, sp = 0;
    for (int t = 0; t < 100; ++t) {
        const unsigned char* ip = in + (size_t)(t * 4 + b) * 512 + lane * 8;
        uchar4 a = *(const uchar4*)ip;
        uchar4 c = *(const uchar4*)(ip + 4);
        float acc = wreg[0] * (float)a.x + wreg[1] * (float)a.y +
                    wreg[2] * (float)a.z + wreg[3] * (float)a.w +
                    wreg[4] * (float)c.x + wreg[5] * (float)c.y +
                    wreg[6] * (float)c.z + wreg[7] * (float)c.w;
#pragma unroll
        for (int off = 32; off > 0; off >>= 1) acc += __shfl_xor(acc, off, 64);
        float s = iir_spike_step(acc, y1, y2, xp, r1, r2, sp);
        if (lane == 0) out[(b * 11 + o) * 100 + t] = s;
    }
}

extern "C" void kernel_launch(void* const* d_in, const int* in_sizes, int n_in,
                              void* d_out, int out_size, void* d_ws, size_t ws_size,
                              hipStream_t stream) {
    const float* s_in = (const float*)d_in[0];
    const float* w1   = (const float*)d_in[1];
    const float* w2   = (const float*)d_in[2];
    const float* w3   = (const float*)d_in[3];
    const float* w4a  = (const float*)d_in[4];
    const float* w4b  = (const float*)d_in[5];
    float* out = (float*)d_out;

    char* ws = (char*)d_ws;
    unsigned long long* s0m  = (unsigned long long*)(ws + 0);          //   409,600
    unsigned long long* s1m  = (unsigned long long*)(ws + 409600);     // 6,553,600
    unsigned*           s2m  = (unsigned*)(ws + 6963200);              // 1,638,400
    unsigned long long* sc2m = (unsigned long long*)(ws + 8601600);    // 3,276,800
    unsigned long long* s3m  = (unsigned long long*)(ws + 11878400);   //   819,200
    unsigned long long* s4m  = (unsigned long long*)(ws + 12697600);   // 1,638,400
    unsigned char*      s5   = (unsigned char*)(ws + 14336000);        // 3,276,800
    unsigned char*      s6   = (unsigned char*)(ws + 17612800);        //   204,800
    float*              w2T  = (float*)(ws + 17817600);                //    73,728
    float*              w3T  = (float*)(ws + 17891328);                //   294,912

    // allow >64KB dynamic LDS for the sparse conv kernels
    hipFuncSetAttribute((const void*)k_sc2, hipFuncAttributeMaxDynamicSharedMemorySize, 73728);
    hipFuncSetAttribute((const void*)k_sc3, hipFuncAttributeMaxDynamicSharedMemorySize, 147456);

    k_wT<<<288, 256, 0, stream>>>(w2, w3, w2T, w3T);
    k_sp0<<<128, 256, 0, stream>>>(s_in, s0m);
    k_sc1<<<2048, 256, 0, stream>>>(s0m, w1, s1m);
    k_sp1<<<512, 256, 0, stream>>>(s1m, s2m);
    k_sc2<<<1024, 256, 73728, stream>>>(s2m, w2T, sc2m);
    k_sp2<<<256, 256, 0, stream>>>(sc2m, s3m);
    k_sc3<<<512, 256, 147456, stream>>>(s3m, w3T, s4m);
    k_sp3<<<128, 256, 0, stream>>>(s4m, s5);
    k_dense4a<<<512, 256, 0, stream>>>(s5, w4a, s6);
    k_dense4b<<<44, 64, 0, stream>>>(s6, w4b, out);
}

// Round 5
// 2119.467 us; speedup vs baseline: 4.9107x; 1.2427x over previous
//
#include <hip/hip_runtime.h>

// SLAYER SRM-alpha constants (f64-computed, f32-cast):
__device__ constexpr float C1f = (float)1.80967483607191914632;   // 2*exp(-0.1)
__device__ constexpr float C2f = (float)0.81873075307798185867;   // exp(-0.2)
__device__ constexpr float C3f = (float)0.24596031111569496638;   // e^0.9/10

__device__ __forceinline__ float iir_spike_step(float acc, float& y1, float& y2, float& xp,
                                                float& r1, float& r2, float& sp) {
#pragma clang fp contract(off)
    float u = C1f * y1 - C2f * y2 + C3f * xp;   // psp output at t (uses x[t-1])
    float r = C1f * r1 - C2f * r2 + C3f * sp;   // alpha response to past spikes
    float s = (u - 20.0f * r >= 10.0f) ? 1.0f : 0.0f;
    y2 = y1; y1 = u; xp = acc;
    r2 = r1; r1 = r; sp = s;
    return s;
}

// ---------------- SP0: pool(2x2 of s_in) + psp + spike -> w-packed row masks
// s0m layout: [t][b][c][h] ulong (bit w). Wave = one row (b,c,h), lane = w.
__global__ void k_sp0(const float* __restrict__ s_in, unsigned long long* __restrict__ s0m) {
    int wid = (blockIdx.x * 256 + threadIdx.x) >> 6;   // 0..511 = (b,c,h)
    int lane = threadIdx.x & 63;                        // w
    int h = wid & 63;
    int c = (wid >> 6) & 1;
    int b = wid >> 7;
    const float* p00 = s_in + ((size_t)(((b * 2 + c) * 128 + 2 * h) * 128 + 2 * lane)) * 100;
    const float* p01 = p00 + 100;
    const float* p10 = p00 + 12800;
    const float* p11 = p10 + 100;
    float y1 = 0, y2 = 0, xp = 0, r1 = 0, r2 = 0, sp = 0;
    for (int t = 0; t < 100; ++t) {
        float cnt = (p00[t] > 0.5f) + (p01[t] > 0.5f) + (p10[t] > 0.5f) + (p11[t] > 0.5f);
        float s = iir_spike_step(11.0f * cnt, y1, y2, xp, r1, r2, sp);
        unsigned long long m = __ballot(s > 0.5f);
        if (lane == 0) s0m[((size_t)(t * 4 + b) * 2 + c) * 64 + h] = m;
    }
}

// ---------------- SC1: 5x5 conv (2ch) via row-mask per-bit iteration (order-exact
// vs dense (c,kh,kw) loop) + psp + spike -> s1m row masks [t][b][o][h] ulong (bit w).
__global__ void k_sc1(const unsigned long long* __restrict__ s0m, const float* __restrict__ w1,
                      unsigned long long* __restrict__ s1m) {
    int hg = blockIdx.x & 15;
    int o  = (blockIdx.x >> 4) & 31;
    int b  = blockIdx.x >> 9;
    __shared__ float wsm[50];               // [c*25 + kh*5 + kw]
    for (int i = threadIdx.x; i < 50; i += 256) wsm[i] = w1[o * 50 + i];
    __syncthreads();
    int h = hg * 4 + (threadIdx.x >> 6);
    int lane = threadIdx.x & 63;            // w
    int sh = lane - 2;
    float y1 = 0, y2 = 0, xp = 0, r1 = 0, r2 = 0, sp = 0;
    for (int t = 0; t < 100; ++t) {
        float acc = 0.0f;
        const unsigned long long* rb = s0m + (size_t)(t * 4 + b) * 128;
#pragma unroll
        for (int c = 0; c < 2; ++c) {
#pragma unroll
            for (int kh = 0; kh < 5; ++kh) {
                int ih = h - 2 + kh;
                unsigned long long m = (ih >= 0 && ih < 64) ? rb[c * 64 + ih] : 0ULL;
                unsigned pat = (sh >= 0) ? ((unsigned)(m >> sh) & 31u)
                                         : (((unsigned)m << (-sh)) & 31u);
                while (pat) {                       // ascending kw: bit-exact vs dense loop
                    int j = __builtin_ctz(pat);
                    pat &= pat - 1;
                    acc += wsm[c * 25 + kh * 5 + j];
                }
            }
        }
        float s = iir_spike_step(acc, y1, y2, xp, r1, r2, sp);
        unsigned long long mm = __ballot(s > 0.5f);
        if (lane == 0) s1m[((size_t)(t * 4 + b) * 32 + o) * 64 + h] = mm;
    }
}

// ---------------- SP1: pool SC1 spikes -> c-packed masks s2m [t][b][32][32] uint (bit c)
// Wave: (b,ho,wo-pair); lane = c(0..31) + 32*q, q = which wo of the pair.
__global__ void k_sp1(const unsigned long long* __restrict__ s1m, unsigned* __restrict__ s2m) {
    int wid = (blockIdx.x * 256 + threadIdx.x) >> 6;   // (b*32+ho)*16+wop
    int lane = threadIdx.x & 63;
    int wop = wid & 15;
    int ho = (wid >> 4) & 31;
    int b = wid >> 9;
    int c = lane & 31;
    int q = lane >> 5;
    int w = wop * 2 + q;                                // output wo
    float y1 = 0, y2 = 0, xp = 0, r1 = 0, r2 = 0, sp = 0;
    for (int t = 0; t < 100; ++t) {
        const unsigned long long* base = s1m + ((size_t)(t * 4 + b) * 32 + c) * 64 + 2 * ho;
        unsigned long long m0 = base[0], m1 = base[1];
        unsigned v0 = (unsigned)(m0 >> (2 * w)) & 3u;
        unsigned v1 = (unsigned)(m1 >> (2 * w)) & 3u;
        float cnt = (float)((v0 & 1) + (v0 >> 1) + (v1 & 1) + (v1 >> 1));
        float s = iir_spike_step(11.0f * cnt, y1, y2, xp, r1, r2, sp);
        unsigned long long mm = __ballot(s > 0.5f);
        if (lane == 0)  s2m[((size_t)(t * 4 + b) * 32 + ho) * 32 + wop * 2]     = (unsigned)mm;
        if (lane == 32) s2m[((size_t)(t * 4 + b) * 32 + ho) * 32 + wop * 2 + 1] = (unsigned)(mm >> 32);
    }
}

// ---------------- weight transposes into ws: wT[pos][c][o]
__global__ void k_wT(const float* __restrict__ w2, const float* __restrict__ w3,
                     float* __restrict__ w2T, float* __restrict__ w3T) {
    int i = blockIdx.x * 256 + threadIdx.x;
    if (i < 9 * 32 * 64) {
        int o = i & 63; int c = (i >> 6) & 31; int p = i >> 11;
        w2T[i] = w2[(o * 32 + c) * 9 + p];
    }
    if (i < 9 * 64 * 128) {
        int o = i & 127; int c = (i >> 7) & 63; int p = i >> 13;
        w3T[i] = w3[(o * 64 + c) * 9 + p];
    }
}

// ---------------- transpose wf4a [512][8192] -> wT4a [8192][512], 64x64 LDS tiles
__global__ void k_wT4a(const float* __restrict__ w, float* __restrict__ wT) {
    __shared__ float tile[64][65];
    int ft = blockIdx.x & 127;   // f tile
    int ot = blockIdx.x >> 7;    // o tile (0..7)
    int j = threadIdx.x & 63;
    int i0 = threadIdx.x >> 6;   // 0..3
    for (int i = i0; i < 64; i += 4)
        tile[i][j] = w[(size_t)(ot * 64 + i) * 8192 + ft * 64 + j];
    __syncthreads();
    for (int i = i0; i < 64; i += 4)
        wT[(size_t)(ft * 64 + i) * 512 + ot * 64 + j] = tile[j][i];
}

// ---------------- SC2: sparse 3x3 conv (32c -> 64o) + psp + spike -> sc2m ulong (bit o)
// Wave = 64 o's of one pixel; mask wave-uniform, scalar ctz loop. LDS [9*32][64] = 72KB.
__global__ void k_sc2(const unsigned* __restrict__ s2m, const float* __restrict__ w2T,
                      unsigned long long* __restrict__ sc2m) {
    extern __shared__ float wl[];
    for (int i = threadIdx.x; i < 9 * 32 * 64; i += 256) wl[i] = w2T[i];
    __syncthreads();
    int pg = blockIdx.x & 255;
    int b = blockIdx.x >> 8;
    int pix = pg * 4 + (threadIdx.x >> 6);
    int h = pix >> 5, w = pix & 31;
    int lane = threadIdx.x & 63;   // o
    float y1 = 0, y2 = 0, xp = 0, r1 = 0, r2 = 0, sp = 0;
    for (int t = 0; t < 100; ++t) {
        const unsigned* mb = s2m + (size_t)(t * 4 + b) * 1024;
        float acc = 0.0f;
#pragma unroll
        for (int kh = 0; kh < 3; ++kh) {
            int ih = h - 1 + kh;
            if (ih < 0 || ih >= 32) continue;
#pragma unroll
            for (int kw = 0; kw < 3; ++kw) {
                int iw = w - 1 + kw;
                if (iw < 0 || iw >= 32) continue;
                unsigned m = __builtin_amdgcn_readfirstlane(mb[ih * 32 + iw]);
                int pbase = (kh * 3 + kw) * 32 * 64;
                while (m) {
                    int c = __builtin_ctz(m);
                    m &= m - 1;
                    acc += wl[pbase + c * 64 + lane];
                }
            }
        }
        float s = iir_spike_step(acc, y1, y2, xp, r1, r2, sp);
        unsigned long long mm = __ballot(s > 0.5f);
        if (lane == 0) sc2m[(size_t)(t * 4 + b) * 1024 + pix] = mm;
    }
}

// ---------------- SP2: pool SC2 masks -> s3m [t][b][16][16] ulong (bit c of 64)
__global__ void k_sp2(const unsigned long long* __restrict__ sc2m,
                      unsigned long long* __restrict__ s3m) {
    int wid = (blockIdx.x * 256 + threadIdx.x) >> 6;   // (b*16+ho)*16+wo
    int lane = threadIdx.x & 63;                        // c
    int wo = wid & 15;
    int ho = (wid >> 4) & 15;
    int b = wid >> 8;
    float y1 = 0, y2 = 0, xp = 0, r1 = 0, r2 = 0, sp = 0;
    for (int t = 0; t < 100; ++t) {
        const unsigned long long* mb = sc2m + (size_t)(t * 4 + b) * 1024 + (2 * ho) * 32 + 2 * wo;
        unsigned long long a0 = mb[0], a1 = mb[1], a2 = mb[32], a3 = mb[33];
        float cnt = (float)(((a0 >> lane) & 1) + ((a1 >> lane) & 1) +
                            ((a2 >> lane) & 1) + ((a3 >> lane) & 1));
        float s = iir_spike_step(11.0f * cnt, y1, y2, xp, r1, r2, sp);
        unsigned long long mm = __ballot(s > 0.5f);
        if (lane == 0) s3m[(size_t)(t * 4 + b) * 256 + ho * 16 + wo] = mm;
    }
}

// ---------------- SC3: sparse 3x3 conv (64c -> 128o, o-half per block) -> s4m [..][pix][2] ulong
// LDS [9*64][64] = 144KB dynamic.
__global__ void k_sc3(const unsigned long long* __restrict__ s3m, const float* __restrict__ w3T,
                      unsigned long long* __restrict__ s4m) {
    extern __shared__ float wl[];
    int half = blockIdx.x & 1;
    int pg = (blockIdx.x >> 1) & 63;
    int b = blockIdx.x >> 7;
    for (int i = threadIdx.x; i < 9 * 64 * 64; i += 256) {
        int o = i & 63; int pc = i >> 6;               // pc = p*64+c
        wl[i] = w3T[pc * 128 + half * 64 + o];
    }
    __syncthreads();
    int pix = pg * 4 + (threadIdx.x >> 6);
    int h = pix >> 4, w = pix & 15;
    int lane = threadIdx.x & 63;   // o within half
    float y1 = 0, y2 = 0, xp = 0, r1 = 0, r2 = 0, sp = 0;
    for (int t = 0; t < 100; ++t) {
        const unsigned long long* mb = s3m + (size_t)(t * 4 + b) * 256;
        float acc = 0.0f;
#pragma unroll
        for (int kh = 0; kh < 3; ++kh) {
            int ih = h - 1 + kh;
            if (ih < 0 || ih >= 16) continue;
#pragma unroll
            for (int kw = 0; kw < 3; ++kw) {
                int iw = w - 1 + kw;
                if (iw < 0 || iw >= 16) continue;
                unsigned long long mm64 = mb[ih * 16 + iw];
                unsigned lo = __builtin_amdgcn_readfirstlane((unsigned)mm64);
                unsigned hi = __builtin_amdgcn_readfirstlane((unsigned)(mm64 >> 32));
                int pbase = (kh * 3 + kw) * 64 * 64;
                while (lo) {
                    int c = __builtin_ctz(lo);
                    lo &= lo - 1;
                    acc += wl[pbase + c * 64 + lane];
                }
                while (hi) {
                    int c = 32 + __builtin_ctz(hi);
                    hi &= hi - 1;
                    acc += wl[pbase + c * 64 + lane];
                }
            }
        }
        float s = iir_spike_step(acc, y1, y2, xp, r1, r2, sp);
        unsigned long long mm = __ballot(s > 0.5f);
        if (lane == 0) s4m[((size_t)(t * 4 + b) * 256 + pix) * 2 + half] = mm;
    }
}

// ---------------- SP3: pool SC3 masks -> pix-packed masks s5m [t][b][c=128] ulong (bit pix)
// Wave = (b,c); lane = output pixel (8x8). Pixel stride in s4m = 2 ulongs.
__global__ void k_sp3(const unsigned long long* __restrict__ s4m,
                      unsigned long long* __restrict__ s5m) {
    int wid = (blockIdx.x * 256 + threadIdx.x) >> 6;   // b*128 + c
    int lane = threadIdx.x & 63;
    int c = wid & 127;
    int b = wid >> 7;
    int half = c >> 6;
    int cbit = c & 63;
    int ho = lane >> 3, wo = lane & 7;
    float y1 = 0, y2 = 0, xp = 0, r1 = 0, r2 = 0, sp = 0;
    for (int t = 0; t < 100; ++t) {
        const unsigned long long* mb =
            s4m + ((size_t)(t * 4 + b) * 256 + (2 * ho) * 16 + 2 * wo) * 2 + half;
        // input pixels: (2ho,2wo)=+0, (2ho,2wo+1)=+2, (2ho+1,2wo)=+32, (2ho+1,2wo+1)=+34
        unsigned long long a0 = mb[0], a1 = mb[2], a2 = mb[32], a3 = mb[34];
        float cnt = (float)(((a0 >> cbit) & 1) + ((a1 >> cbit) & 1) +
                            ((a2 >> cbit) & 1) + ((a3 >> cbit) & 1));
        float s = iir_spike_step(11.0f * cnt, y1, y2, xp, r1, r2, sp);
        unsigned long long mm = __ballot(s > 0.5f);
        if (lane == 0) s5m[(size_t)(t * 4 + b) * 128 + c] = mm;
    }
}

// ---------------- SF4a GEMM: acc[tb][512] = sum over active f of wT[f][o]
// Wave = (tb, o-tile of 64); masks wave-uniform, scalar ctz walk, ascending f.
__global__ void k_gemm4a(const unsigned long long* __restrict__ s5m,
                         const float* __restrict__ wT,
                         float* __restrict__ acc_out) {
    int wg = blockIdx.x * 4 + (threadIdx.x >> 6);   // 3200 waves
    int lane = threadIdx.x & 63;
    int ot = wg & 7;
    int tb = wg >> 3;                               // 0..399
    const unsigned long long* mp = s5m + (size_t)tb * 128;
    const float* wbase = wT + ot * 64 + lane;
    float acc = 0.0f;
    for (int c = 0; c < 128; ++c) {
        unsigned long long m = mp[c];
        unsigned lo = __builtin_amdgcn_readfirstlane((unsigned)m);
        unsigned hi = __builtin_amdgcn_readfirstlane((unsigned)(m >> 32));
        int fbase = c * 64;
        while (lo) {
            int j = __builtin_ctz(lo);
            lo &= lo - 1;
            acc += wbase[(size_t)(fbase + j) * 512];
        }
        while (hi) {
            int j = __builtin_ctz(hi);
            hi &= hi - 1;
            acc += wbase[(size_t)(fbase + 32 + j) * 512];
        }
    }
    acc_out[(size_t)tb * 512 + ot * 64 + lane] = acc;
}

// ---------------- SF4a IIR: per-(b,o) scan over precomputed acc -> u8 spikes s6 [t][b][512]
__global__ void k_iir4a(const float* __restrict__ accbuf, unsigned char* __restrict__ s6) {
    int id = blockIdx.x * 64 + threadIdx.x;   // 2048 = b*512+o
    int b = id >> 9, o = id & 511;
    float y1 = 0, y2 = 0, xp = 0, r1 = 0, r2 = 0, sp = 0;
    for (int t = 0; t < 100; ++t) {
        float a = accbuf[(size_t)(t * 4 + b) * 512 + o];
        float s = iir_spike_step(a, y1, y2, xp, r1, r2, sp);
        s6[(size_t)(t * 4 + b) * 512 + o] = (unsigned char)s;
    }
}

// ---------------- SF4b: dense 512->11 -> final out [B][11][T] f32
__global__ void k_dense4b(const unsigned char* __restrict__ in,
                          const float* __restrict__ wt,
                          float* __restrict__ out) {
    int wid = blockIdx.x;      // 44 = (b,o)
    int lane = threadIdx.x;
    int o = wid % 11;
    int b = wid / 11;
    float wreg[8];
    const float* wp = wt + o * 512 + lane * 8;
#pragma unroll
    for (int k = 0; k < 8; ++k) wreg[k] = wp[k];
    float y1 = 0, y2 = 0, xp = 0, r1 = 0, r2 = 0, sp = 0;
    for (int t = 0; t < 100; ++t) {
        const unsigned char* ip = in + (size_t)(t * 4 + b) * 512 + lane * 8;
        uchar4 a = *(const uchar4*)ip;
        uchar4 c = *(const uchar4*)(ip + 4);
        float acc = wreg[0] * (float)a.x + wreg[1] * (float)a.y +
                    wreg[2] * (float)a.z + wreg[3] * (float)a.w +
                    wreg[4] * (float)c.x + wreg[5] * (float)c.y +
                    wreg[6] * (float)c.z + wreg[7] * (float)c.w;
#pragma unroll
        for (int off = 32; off > 0; off >>= 1) acc += __shfl_xor(acc, off, 64);
        float s = iir_spike_step(acc, y1, y2, xp, r1, r2, sp);
        if (lane == 0) out[(b * 11 + o) * 100 + t] = s;
    }
}

extern "C" void kernel_launch(void* const* d_in, const int* in_sizes, int n_in,
                              void* d_out, int out_size, void* d_ws, size_t ws_size,
                              hipStream_t stream) {
    const float* s_in = (const float*)d_in[0];
    const float* w1   = (const float*)d_in[1];
    const float* w2   = (const float*)d_in[2];
    const float* w3   = (const float*)d_in[3];
    const float* w4a  = (const float*)d_in[4];
    const float* w4b  = (const float*)d_in[5];
    float* out = (float*)d_out;

    char* ws = (char*)d_ws;
    unsigned long long* s0m  = (unsigned long long*)(ws + 0);          //   409,600
    unsigned long long* s1m  = (unsigned long long*)(ws + 409600);     // 6,553,600
    unsigned*           s2m  = (unsigned*)(ws + 6963200);              // 1,638,400
    unsigned long long* sc2m = (unsigned long long*)(ws + 8601600);    // 3,276,800
    unsigned long long* s3m  = (unsigned long long*)(ws + 11878400);   //   819,200
    unsigned long long* s4m  = (unsigned long long*)(ws + 12697600);   // 1,638,400
    unsigned long long* s5m  = (unsigned long long*)(ws + 14336000);   //   409,600
    unsigned char*      s6   = (unsigned char*)(ws + 14745600);        //   204,800
    float*              accA = (float*)(ws + 14950400);                //   819,200
    float*              w2T  = (float*)(ws + 15769600);                //    73,728
    float*              w3T  = (float*)(ws + 15843328);                //   294,912
    float*              wT4a = (float*)(ws + 16138240);                // 16,777,216  (end ~32.9MB)

    // allow >64KB dynamic LDS for the sparse conv kernels
    hipFuncSetAttribute((const void*)k_sc2, hipFuncAttributeMaxDynamicSharedMemorySize, 73728);
    hipFuncSetAttribute((const void*)k_sc3, hipFuncAttributeMaxDynamicSharedMemorySize, 147456);

    k_wT<<<288, 256, 0, stream>>>(w2, w3, w2T, w3T);
    k_wT4a<<<1024, 256, 0, stream>>>(w4a, wT4a);
    k_sp0<<<128, 256, 0, stream>>>(s_in, s0m);
    k_sc1<<<2048, 256, 0, stream>>>(s0m, w1, s1m);
    k_sp1<<<512, 256, 0, stream>>>(s1m, s2m);
    k_sc2<<<1024, 256, 73728, stream>>>(s2m, w2T, sc2m);
    k_sp2<<<256, 256, 0, stream>>>(sc2m, s3m);
    k_sc3<<<512, 256, 147456, stream>>>(s3m, w3T, s4m);
    k_sp3<<<128, 256, 0, stream>>>(s4m, s5m);
    k_gemm4a<<<800, 256, 0, stream>>>(s5m, wT4a, accA);
    k_iir4a<<<32, 64, 0, stream>>>(accA, s6);
    k_dense4b<<<44, 64, 0, stream>>>(s6, w4b, out);
}

// Round 6
// 1516.887 us; speedup vs baseline: 6.8614x; 1.3972x over previous
//
#include <hip/hip_runtime.h>

typedef unsigned long long ull;

// SLAYER SRM-alpha constants (f64-computed, f32-cast):
__device__ constexpr float C1f = (float)1.80967483607191914632;   // 2*exp(-0.1)
__device__ constexpr float C2f = (float)0.81873075307798185867;   // exp(-0.2)
__device__ constexpr float C3f = (float)0.24596031111569496638;   // e^0.9/10

__device__ __forceinline__ float iir_spike_step(float acc, float& y1, float& y2, float& xp,
                                                float& r1, float& r2, float& sp) {
#pragma clang fp contract(off)
    float u = C1f * y1 - C2f * y2 + C3f * xp;   // psp output at t (uses x[t-1])
    float r = C1f * r1 - C2f * r2 + C3f * sp;   // alpha response to past spikes
    float s = (u - 20.0f * r >= 10.0f) ? 1.0f : 0.0f;
    y2 = y1; y1 = u; xp = acc;
    r2 = r1; r1 = r; sp = s;
    return s;
}

// 4-wide batched sparse accumulate over a wave-uniform 64-bit mask.
// base[c*64 + lane]; adds strictly ascending c (bit-exact vs 1-at-a-time walk).
__device__ __forceinline__ void sparse_acc64(float& acc, ull m,
                                             const float* __restrict__ base, int lane) {
    while (m) {
        ull m1 = m & (m - 1);
        ull m2 = m1 & (m1 - 1);
        ull m3 = m2 & (m2 - 1);
        if (m3) {
            int c0 = __builtin_ctzll(m);
            int c1 = __builtin_ctzll(m1);
            int c2 = __builtin_ctzll(m2);
            int c3 = __builtin_ctzll(m3);
            float w0 = base[c0 * 64 + lane];
            float w1 = base[c1 * 64 + lane];
            float w2 = base[c2 * 64 + lane];
            float w3 = base[c3 * 64 + lane];
            acc += w0; acc += w1; acc += w2; acc += w3;
            m = m3 & (m3 - 1);
        } else {
            acc += base[__builtin_ctzll(m) * 64 + lane];
            m = m1;
        }
    }
}

// ---------------- SP0: pool(2x2 of s_in) + psp + spike -> w-packed row masks
__global__ void k_sp0(const float* __restrict__ s_in, ull* __restrict__ s0m) {
    int wid = (blockIdx.x * 256 + threadIdx.x) >> 6;   // 0..511 = (b,c,h)
    int lane = threadIdx.x & 63;                        // w
    int h = wid & 63;
    int c = (wid >> 6) & 1;
    int b = wid >> 7;
    const float* p00 = s_in + ((size_t)(((b * 2 + c) * 128 + 2 * h) * 128 + 2 * lane)) * 100;
    const float* p01 = p00 + 100;
    const float* p10 = p00 + 12800;
    const float* p11 = p10 + 100;
    float y1 = 0, y2 = 0, xp = 0, r1 = 0, r2 = 0, sp = 0;
    for (int t = 0; t < 100; ++t) {
        float cnt = (p00[t] > 0.5f) + (p01[t] > 0.5f) + (p10[t] > 0.5f) + (p11[t] > 0.5f);
        float s = iir_spike_step(11.0f * cnt, y1, y2, xp, r1, r2, sp);
        ull m = __ballot(s > 0.5f);
        if (lane == 0) s0m[((size_t)(t * 4 + b) * 2 + c) * 64 + h] = m;
    }
}

// ---------------- SC1: 5x5 conv (2ch) via row-mask per-bit iteration + psp + spike
__global__ void k_sc1(const ull* __restrict__ s0m, const float* __restrict__ w1,
                      ull* __restrict__ s1m) {
    int hg = blockIdx.x & 15;
    int o  = (blockIdx.x >> 4) & 31;
    int b  = blockIdx.x >> 9;
    __shared__ float wsm[50];               // [c*25 + kh*5 + kw]
    for (int i = threadIdx.x; i < 50; i += 256) wsm[i] = w1[o * 50 + i];
    __syncthreads();
    int h = hg * 4 + (threadIdx.x >> 6);
    int lane = threadIdx.x & 63;            // w
    int sh = lane - 2;
    float y1 = 0, y2 = 0, xp = 0, r1 = 0, r2 = 0, sp = 0;
    for (int t = 0; t < 100; ++t) {
        float acc = 0.0f;
        const ull* rb = s0m + (size_t)(t * 4 + b) * 128;
#pragma unroll
        for (int c = 0; c < 2; ++c) {
#pragma unroll
            for (int kh = 0; kh < 5; ++kh) {
                int ih = h - 2 + kh;
                ull m = (ih >= 0 && ih < 64) ? rb[c * 64 + ih] : 0ULL;
                unsigned pat = (sh >= 0) ? ((unsigned)(m >> sh) & 31u)
                                         : (((unsigned)m << (-sh)) & 31u);
                while (pat) {                       // ascending kw: bit-exact vs dense loop
                    int j = __builtin_ctz(pat);
                    pat &= pat - 1;
                    acc += wsm[c * 25 + kh * 5 + j];
                }
            }
        }
        float s = iir_spike_step(acc, y1, y2, xp, r1, r2, sp);
        ull mm = __ballot(s > 0.5f);
        if (lane == 0) s1m[((size_t)(t * 4 + b) * 32 + o) * 64 + h] = mm;
    }
}

// ---------------- SP1: pool SC1 spikes -> c-packed masks s2m [t][b][32][32] uint (bit c)
__global__ void k_sp1(const ull* __restrict__ s1m, unsigned* __restrict__ s2m) {
    int wid = (blockIdx.x * 256 + threadIdx.x) >> 6;   // (b*32+ho)*16+wop
    int lane = threadIdx.x & 63;
    int wop = wid & 15;
    int ho = (wid >> 4) & 31;
    int b = wid >> 9;
    int c = lane & 31;
    int q = lane >> 5;
    int w = wop * 2 + q;                                // output wo
    float y1 = 0, y2 = 0, xp = 0, r1 = 0, r2 = 0, sp = 0;
    for (int t = 0; t < 100; ++t) {
        const ull* base = s1m + ((size_t)(t * 4 + b) * 32 + c) * 64 + 2 * ho;
        ull m0 = base[0], m1 = base[1];
        unsigned v0 = (unsigned)(m0 >> (2 * w)) & 3u;
        unsigned v1 = (unsigned)(m1 >> (2 * w)) & 3u;
        float cnt = (float)((v0 & 1) + (v0 >> 1) + (v1 & 1) + (v1 >> 1));
        float s = iir_spike_step(11.0f * cnt, y1, y2, xp, r1, r2, sp);
        ull mm = __ballot(s > 0.5f);
        if (lane == 0)  s2m[((size_t)(t * 4 + b) * 32 + ho) * 32 + wop * 2]     = (unsigned)mm;
        if (lane == 32) s2m[((size_t)(t * 4 + b) * 32 + ho) * 32 + wop * 2 + 1] = (unsigned)(mm >> 32);
    }
}

// ---------------- weight transposes into ws: wT[pos][c][o]
__global__ void k_wT(const float* __restrict__ w2, const float* __restrict__ w3,
                     float* __restrict__ w2T, float* __restrict__ w3T) {
    int i = blockIdx.x * 256 + threadIdx.x;
    if (i < 9 * 32 * 64) {
        int o = i & 63; int c = (i >> 6) & 31; int p = i >> 11;
        w2T[i] = w2[(o * 32 + c) * 9 + p];
    }
    if (i < 9 * 64 * 128) {
        int o = i & 127; int c = (i >> 7) & 63; int p = i >> 13;
        w3T[i] = w3[(o * 64 + c) * 9 + p];
    }
}

// ---------------- transpose wf4a [512][8192] -> wT4a [8192][512], 64x64 LDS tiles
__global__ void k_wT4a(const float* __restrict__ w, float* __restrict__ wT) {
    __shared__ float tile[64][65];
    int ft = blockIdx.x & 127;   // f tile
    int ot = blockIdx.x >> 7;    // o tile (0..7)
    int j = threadIdx.x & 63;
    int i0 = threadIdx.x >> 6;   // 0..3
    for (int i = i0; i < 64; i += 4)
        tile[i][j] = w[(size_t)(ot * 64 + i) * 8192 + ft * 64 + j];
    __syncthreads();
    for (int i = i0; i < 64; i += 4)
        wT[(size_t)(ft * 64 + i) * 512 + ot * 64 + j] = tile[j][i];
}

// ---------------- SC2: sparse 3x3 conv (32c -> 64o) + psp + spike -> sc2m ulong (bit o)
// 256 blocks x 1024 threads (16 waves): task = b*1024+pix. LDS 72KB -> 2 blocks/CU (full occ).
__global__ __launch_bounds__(1024) void k_sc2(const unsigned* __restrict__ s2m,
                                              const float* __restrict__ w2T,
                                              ull* __restrict__ sc2m) {
    extern __shared__ float wl[];
    for (int i = threadIdx.x; i < 9 * 32 * 64; i += 1024) wl[i] = w2T[i];
    __syncthreads();
    int task = blockIdx.x * 16 + (threadIdx.x >> 6);   // 0..4095
    int pix = task & 1023;
    int b = task >> 10;
    int h = pix >> 5, w = pix & 31;
    int lane = threadIdx.x & 63;   // o
    float y1 = 0, y2 = 0, xp = 0, r1 = 0, r2 = 0, sp = 0;
    for (int t = 0; t < 100; ++t) {
        const unsigned* mb = s2m + (size_t)(t * 4 + b) * 1024;
        float acc = 0.0f;
#pragma unroll
        for (int kh = 0; kh < 3; ++kh) {
            int ih = h - 1 + kh;
            if (ih < 0 || ih >= 32) continue;
#pragma unroll
            for (int kw = 0; kw < 3; ++kw) {
                int iw = w - 1 + kw;
                if (iw < 0 || iw >= 32) continue;
                unsigned m = __builtin_amdgcn_readfirstlane(mb[ih * 32 + iw]);
                sparse_acc64(acc, (ull)m, wl + (kh * 3 + kw) * 32 * 64, lane);
            }
        }
        float s = iir_spike_step(acc, y1, y2, xp, r1, r2, sp);
        ull mm = __ballot(s > 0.5f);
        if (lane == 0) sc2m[(size_t)(t * 4 + b) * 1024 + pix] = mm;
    }
}

// ---------------- SP2: pool SC2 masks -> s3m [t][b][16][16] ulong (bit c of 64)
__global__ void k_sp2(const ull* __restrict__ sc2m, ull* __restrict__ s3m) {
    int wid = (blockIdx.x * 256 + threadIdx.x) >> 6;   // (b*16+ho)*16+wo
    int lane = threadIdx.x & 63;                        // c
    int wo = wid & 15;
    int ho = (wid >> 4) & 15;
    int b = wid >> 8;
    float y1 = 0, y2 = 0, xp = 0, r1 = 0, r2 = 0, sp = 0;
    for (int t = 0; t < 100; ++t) {
        const ull* mb = sc2m + (size_t)(t * 4 + b) * 1024 + (2 * ho) * 32 + 2 * wo;
        ull a0 = mb[0], a1 = mb[1], a2 = mb[32], a3 = mb[33];
        float cnt = (float)(((a0 >> lane) & 1) + ((a1 >> lane) & 1) +
                            ((a2 >> lane) & 1) + ((a3 >> lane) & 1));
        float s = iir_spike_step(11.0f * cnt, y1, y2, xp, r1, r2, sp);
        ull mm = __ballot(s > 0.5f);
        if (lane == 0) s3m[(size_t)(t * 4 + b) * 256 + ho * 16 + wo] = mm;
    }
}

// ---------------- SC3: sparse 3x3 conv (64c -> 128o, o-half per block) -> s4m [..][pix][2]
// 256 blocks x 512 threads (8 waves): block = (b, pixgroup, half). LDS 144KB, 1 block/CU.
__global__ __launch_bounds__(512) void k_sc3(const ull* __restrict__ s3m,
                                             const float* __restrict__ w3T,
                                             ull* __restrict__ s4m) {
    extern __shared__ float wl[];
    int half = blockIdx.x & 1;
    int rest = blockIdx.x >> 1;          // 0..127 = b*32 + pg
    int pg = rest & 31;
    int b = rest >> 5;
    for (int i = threadIdx.x; i < 9 * 64 * 64; i += 512) {
        int o = i & 63; int pc = i >> 6;               // pc = p*64+c
        wl[i] = w3T[pc * 128 + half * 64 + o];
    }
    __syncthreads();
    int pix = pg * 8 + (threadIdx.x >> 6);
    int h = pix >> 4, w = pix & 15;
    int lane = threadIdx.x & 63;   // o within half
    float y1 = 0, y2 = 0, xp = 0, r1 = 0, r2 = 0, sp = 0;
    for (int t = 0; t < 100; ++t) {
        const ull* mb = s3m + (size_t)(t * 4 + b) * 256;
        float acc = 0.0f;
#pragma unroll
        for (int kh = 0; kh < 3; ++kh) {
            int ih = h - 1 + kh;
            if (ih < 0 || ih >= 16) continue;
#pragma unroll
            for (int kw = 0; kw < 3; ++kw) {
                int iw = w - 1 + kw;
                if (iw < 0 || iw >= 16) continue;
                ull mm64 = mb[ih * 16 + iw];
                unsigned lo = __builtin_amdgcn_readfirstlane((unsigned)mm64);
                unsigned hi = __builtin_amdgcn_readfirstlane((unsigned)(mm64 >> 32));
                ull m = ((ull)hi << 32) | lo;
                sparse_acc64(acc, m, wl + (kh * 3 + kw) * 64 * 64, lane);
            }
        }
        float s = iir_spike_step(acc, y1, y2, xp, r1, r2, sp);
        ull mm = __ballot(s > 0.5f);
        if (lane == 0) s4m[((size_t)(t * 4 + b) * 256 + pix) * 2 + half] = mm;
    }
}

// ---------------- SP3: pool SC3 masks -> pix-packed masks s5m [t][b][c=128] ulong (bit pix)
__global__ void k_sp3(const ull* __restrict__ s4m, ull* __restrict__ s5m) {
    int wid = (blockIdx.x * 256 + threadIdx.x) >> 6;   // b*128 + c
    int lane = threadIdx.x & 63;
    int c = wid & 127;
    int b = wid >> 7;
    int half = c >> 6;
    int cbit = c & 63;
    int ho = lane >> 3, wo = lane & 7;
    float y1 = 0, y2 = 0, xp = 0, r1 = 0, r2 = 0, sp = 0;
    for (int t = 0; t < 100; ++t) {
        const ull* mb = s4m + ((size_t)(t * 4 + b) * 256 + (2 * ho) * 16 + 2 * wo) * 2 + half;
        // input pixels: (2ho,2wo)=+0, (2ho,2wo+1)=+2, (2ho+1,2wo)=+32, (2ho+1,2wo+1)=+34
        ull a0 = mb[0], a1 = mb[2], a2 = mb[32], a3 = mb[34];
        float cnt = (float)(((a0 >> cbit) & 1) + ((a1 >> cbit) & 1) +
                            ((a2 >> cbit) & 1) + ((a3 >> cbit) & 1));
        float s = iir_spike_step(11.0f * cnt, y1, y2, xp, r1, r2, sp);
        ull mm = __ballot(s > 0.5f);
        if (lane == 0) s5m[(size_t)(t * 4 + b) * 128 + c] = mm;
    }
}

// ---------------- SF4a GEMM: acc[tb][512] = sum over active f of wT[f][o], batched walk
__global__ void k_gemm4a(const ull* __restrict__ s5m,
                         const float* __restrict__ wT,
                         float* __restrict__ acc_out) {
    int wg = blockIdx.x * 4 + (threadIdx.x >> 6);   // 3200 waves
    int lane = threadIdx.x & 63;
    int ot = wg & 7;
    int tb = wg >> 3;                               // 0..399
    const ull* mp = s5m + (size_t)tb * 128;
    const float* wbase = wT + ot * 64 + lane;
    float acc = 0.0f;
    for (int c = 0; c < 128; ++c) {
        ull mv = mp[c];
        unsigned lo = __builtin_amdgcn_readfirstlane((unsigned)mv);
        unsigned hi = __builtin_amdgcn_readfirstlane((unsigned)(mv >> 32));
        ull m = ((ull)hi << 32) | lo;
        const float* wb = wbase + (size_t)(c * 64) * 512;
        while (m) {
            ull m1 = m & (m - 1);
            ull m2 = m1 & (m1 - 1);
            ull m3 = m2 & (m2 - 1);
            if (m3) {
                int c0 = __builtin_ctzll(m);
                int c1 = __builtin_ctzll(m1);
                int c2 = __builtin_ctzll(m2);
                int c3 = __builtin_ctzll(m3);
                float w0 = wb[(size_t)c0 * 512];
                float w1 = wb[(size_t)c1 * 512];
                float w2 = wb[(size_t)c2 * 512];
                float w3 = wb[(size_t)c3 * 512];
                acc += w0; acc += w1; acc += w2; acc += w3;
                m = m3 & (m3 - 1);
            } else {
                acc += wb[(size_t)__builtin_ctzll(m) * 512];
                m = m1;
            }
        }
    }
    acc_out[(size_t)tb * 512 + ot * 64 + lane] = acc;
}

// ---------------- SF4a IIR: per-(b,o) scan over precomputed acc -> u8 spikes s6 [t][b][512]
__global__ void k_iir4a(const float* __restrict__ accbuf, unsigned char* __restrict__ s6) {
    int id = blockIdx.x * 64 + threadIdx.x;   // 2048 = b*512+o
    int b = id >> 9, o = id & 511;
    float y1 = 0, y2 = 0, xp = 0, r1 = 0, r2 = 0, sp = 0;
    for (int t = 0; t < 100; ++t) {
        float a = accbuf[(size_t)(t * 4 + b) * 512 + o];
        float s = iir_spike_step(a, y1, y2, xp, r1, r2, sp);
        s6[(size_t)(t * 4 + b) * 512 + o] = (unsigned char)s;
    }
}

// ---------------- SF4b: dense 512->11 -> final out [B][11][T] f32
__global__ void k_dense4b(const unsigned char* __restrict__ in,
                          const float* __restrict__ wt,
                          float* __restrict__ out) {
    int wid = blockIdx.x;      // 44 = (b,o)
    int lane = threadIdx.x;
    int o = wid % 11;
    int b = wid / 11;
    float wreg[8];
    const float* wp = wt + o * 512 + lane * 8;
#pragma unroll
    for (int k = 0; k < 8; ++k) wreg[k] = wp[k];
    float y1 = 0, y2 = 0, xp = 0, r1 = 0, r2 = 0, sp = 0;
    for (int t = 0; t < 100; ++t) {
        const unsigned char* ip = in + (size_t)(t * 4 + b) * 512 + lane * 8;
        uchar4 a = *(const uchar4*)ip;
        uchar4 c = *(const uchar4*)(ip + 4);
        float acc = wreg[0] * (float)a.x + wreg[1] * (float)a.y +
                    wreg[2] * (float)a.z + wreg[3] * (float)a.w +
                    wreg[4] * (float)c.x + wreg[5] * (float)c.y +
                    wreg[6] * (float)c.z + wreg[7] * (float)c.w;
#pragma unroll
        for (int off = 32; off > 0; off >>= 1) acc += __shfl_xor(acc, off, 64);
        float s = iir_spike_step(acc, y1, y2, xp, r1, r2, sp);
        if (lane == 0) out[(b * 11 + o) * 100 + t] = s;
    }
}

extern "C" void kernel_launch(void* const* d_in, const int* in_sizes, int n_in,
                              void* d_out, int out_size, void* d_ws, size_t ws_size,
                              hipStream_t stream) {
    const float* s_in = (const float*)d_in[0];
    const float* w1   = (const float*)d_in[1];
    const float* w2   = (const float*)d_in[2];
    const float* w3   = (const float*)d_in[3];
    const float* w4a  = (const float*)d_in[4];
    const float* w4b  = (const float*)d_in[5];
    float* out = (float*)d_out;

    char* ws = (char*)d_ws;
    ull*           s0m  = (ull*)(ws + 0);              //   409,600
    ull*           s1m  = (ull*)(ws + 409600);         // 6,553,600
    unsigned*      s2m  = (unsigned*)(ws + 6963200);   // 1,638,400
    ull*           sc2m = (ull*)(ws + 8601600);        // 3,276,800
    ull*           s3m  = (ull*)(ws + 11878400);       //   819,200
    ull*           s4m  = (ull*)(ws + 12697600);       // 1,638,400
    ull*           s5m  = (ull*)(ws + 14336000);       //   409,600
    unsigned char* s6   = (unsigned char*)(ws + 14745600);  //   204,800
    float*         accA = (float*)(ws + 14950400);     //   819,200
    float*         w2T  = (float*)(ws + 15769600);     //    73,728
    float*         w3T  = (float*)(ws + 15843328);     //   294,912
    float*         wT4a = (float*)(ws + 16138240);     // 16,777,216  (end ~32.9MB)

    // allow >64KB dynamic LDS for the sparse conv kernels
    hipFuncSetAttribute((const void*)k_sc2, hipFuncAttributeMaxDynamicSharedMemorySize, 73728);
    hipFuncSetAttribute((const void*)k_sc3, hipFuncAttributeMaxDynamicSharedMemorySize, 147456);

    k_wT<<<288, 256, 0, stream>>>(w2, w3, w2T, w3T);
    k_wT4a<<<1024, 256, 0, stream>>>(w4a, wT4a);
    k_sp0<<<128, 256, 0, stream>>>(s_in, s0m);
    k_sc1<<<2048, 256, 0, stream>>>(s0m, w1, s1m);
    k_sp1<<<512, 256, 0, stream>>>(s1m, s2m);
    k_sc2<<<256, 1024, 73728, stream>>>(s2m, w2T, sc2m);
    k_sp2<<<256, 256, 0, stream>>>(sc2m, s3m);
    k_sc3<<<256, 512, 147456, stream>>>(s3m, w3T, s4m);
    k_sp3<<<128, 256, 0, stream>>>(s4m, s5m);
    k_gemm4a<<<800, 256, 0, stream>>>(s5m, wT4a, accA);
    k_iir4a<<<32, 64, 0, stream>>>(accA, s6);
    k_dense4b<<<44, 64, 0, stream>>>(s6, w4b, out);
}

// Round 7
// 1427.344 us; speedup vs baseline: 7.2919x; 1.0627x over previous
//
#include <hip/hip_runtime.h>

typedef unsigned long long ull;

// SLAYER SRM-alpha constants (f64-computed, f32-cast):
__device__ constexpr float C1f = (float)1.80967483607191914632;   // 2*exp(-0.1)
__device__ constexpr float C2f = (float)0.81873075307798185867;   // exp(-0.2)
__device__ constexpr float C3f = (float)0.24596031111569496638;   // e^0.9/10

__device__ __forceinline__ float iir_spike_step(float acc, float& y1, float& y2, float& xp,
                                                float& r1, float& r2, float& sp) {
#pragma clang fp contract(off)
    float u = C1f * y1 - C2f * y2 + C3f * xp;   // psp output at t (uses x[t-1])
    float r = C1f * r1 - C2f * r2 + C3f * sp;   // alpha response to past spikes
    float s = (u - 20.0f * r >= 10.0f) ? 1.0f : 0.0f;
    y2 = y1; y1 = u; xp = acc;
    r2 = r1; r1 = r; sp = s;
    return s;
}

// 4-wide batched sparse accumulate over a wave-uniform 64-bit mask.
// base[c*64 + lane]; adds strictly ascending c (bit-exact vs 1-at-a-time walk).
__device__ __forceinline__ void sparse_acc64(float& acc, ull m,
                                             const float* __restrict__ base, int lane) {
    while (m) {
        ull m1 = m & (m - 1);
        ull m2 = m1 & (m1 - 1);
        ull m3 = m2 & (m2 - 1);
        if (m3) {
            int c0 = __builtin_ctzll(m);
            int c1 = __builtin_ctzll(m1);
            int c2 = __builtin_ctzll(m2);
            int c3 = __builtin_ctzll(m3);
            float w0 = base[c0 * 64 + lane];
            float w1 = base[c1 * 64 + lane];
            float w2 = base[c2 * 64 + lane];
            float w3 = base[c3 * 64 + lane];
            acc += w0; acc += w1; acc += w2; acc += w3;
            m = m3 & (m3 - 1);
        } else {
            acc += base[__builtin_ctzll(m) * 64 + lane];
            m = m1;
        }
    }
}

// ---------------- SP0: pool(2x2 of s_in) + psp + spike -> w-packed row masks
__global__ void k_sp0(const float* __restrict__ s_in, ull* __restrict__ s0m) {
    int wid = (blockIdx.x * 256 + threadIdx.x) >> 6;   // 0..511 = (b,c,h)
    int lane = threadIdx.x & 63;                        // w
    int h = wid & 63;
    int c = (wid >> 6) & 1;
    int b = wid >> 7;
    const float* p00 = s_in + ((size_t)(((b * 2 + c) * 128 + 2 * h) * 128 + 2 * lane)) * 100;
    const float* p01 = p00 + 100;
    const float* p10 = p00 + 12800;
    const float* p11 = p10 + 100;
    float y1 = 0, y2 = 0, xp = 0, r1 = 0, r2 = 0, sp = 0;
    for (int t = 0; t < 100; ++t) {
        float cnt = (p00[t] > 0.5f) + (p01[t] > 0.5f) + (p10[t] > 0.5f) + (p11[t] > 0.5f);
        float s = iir_spike_step(11.0f * cnt, y1, y2, xp, r1, r2, sp);
        ull m = __ballot(s > 0.5f);
        if (lane == 0) s0m[((size_t)(t * 4 + b) * 2 + c) * 64 + h] = m;
    }
}

// ---------------- SC1: 5x5 conv (2ch) via 32-entry row LUT + psp + spike
// lut[(c*5+kh)*32 + pat] = ascending-kw sum of active weights in that row.
// pat is per-lane but the LUT window base is wave-uniform: <=2-way bank aliasing (free).
__global__ void k_sc1(const ull* __restrict__ s0m, const float* __restrict__ w1,
                      ull* __restrict__ s1m) {
    int hg = blockIdx.x & 15;
    int o  = (blockIdx.x >> 4) & 31;
    int b  = blockIdx.x >> 9;
    __shared__ float lut[320];              // [(c*5+kh)*32 + pat]
    for (int i = threadIdx.x; i < 320; i += 256) {
        int pat = i & 31, ckh = i >> 5;     // ckh = c*5+kh
        const float* wr = w1 + (o * 10 + ckh) * 5;
        float s = 0.0f;
        for (int j = 0; j < 5; ++j) if (pat & (1 << j)) s += wr[j];   // ascending kw
        lut[i] = s;
    }
    __syncthreads();
    int h = hg * 4 + (threadIdx.x >> 6);
    int lane = threadIdx.x & 63;            // w
    int sh = lane - 2;
    float y1 = 0, y2 = 0, xp = 0, r1 = 0, r2 = 0, sp = 0;
    for (int t = 0; t < 100; ++t) {
        float acc = 0.0f;
        const ull* rb = s0m + (size_t)(t * 4 + b) * 128;
#pragma unroll
        for (int c = 0; c < 2; ++c) {
#pragma unroll
            for (int kh = 0; kh < 5; ++kh) {
                int ih = h - 2 + kh;
                ull m = (ih >= 0 && ih < 64) ? rb[c * 64 + ih] : 0ULL;
                unsigned pat = (sh >= 0) ? ((unsigned)(m >> sh) & 31u)
                                         : (((unsigned)m << (-sh)) & 31u);
                acc += lut[(c * 5 + kh) * 32 + pat];
            }
        }
        float s = iir_spike_step(acc, y1, y2, xp, r1, r2, sp);
        ull mm = __ballot(s > 0.5f);
        if (lane == 0) s1m[((size_t)(t * 4 + b) * 32 + o) * 64 + h] = mm;
    }
}

// ---------------- SP1: pool SC1 spikes -> c-packed masks s2m [t][b][32][32] uint (bit c)
__global__ void k_sp1(const ull* __restrict__ s1m, unsigned* __restrict__ s2m) {
    int wid = (blockIdx.x * 256 + threadIdx.x) >> 6;   // (b*32+ho)*16+wop
    int lane = threadIdx.x & 63;
    int wop = wid & 15;
    int ho = (wid >> 4) & 31;
    int b = wid >> 9;
    int c = lane & 31;
    int q = lane >> 5;
    int w = wop * 2 + q;                                // output wo
    float y1 = 0, y2 = 0, xp = 0, r1 = 0, r2 = 0, sp = 0;
    for (int t = 0; t < 100; ++t) {
        const ull* base = s1m + ((size_t)(t * 4 + b) * 32 + c) * 64 + 2 * ho;
        ull m0 = base[0], m1 = base[1];
        unsigned v0 = (unsigned)(m0 >> (2 * w)) & 3u;
        unsigned v1 = (unsigned)(m1 >> (2 * w)) & 3u;
        float cnt = (float)((v0 & 1) + (v0 >> 1) + (v1 & 1) + (v1 >> 1));
        float s = iir_spike_step(11.0f * cnt, y1, y2, xp, r1, r2, sp);
        ull mm = __ballot(s > 0.5f);
        if (lane == 0)  s2m[((size_t)(t * 4 + b) * 32 + ho) * 32 + wop * 2]     = (unsigned)mm;
        if (lane == 32) s2m[((size_t)(t * 4 + b) * 32 + ho) * 32 + wop * 2 + 1] = (unsigned)(mm >> 32);
    }
}

// ---------------- weight transposes into ws: wT[pos][c][o]
__global__ void k_wT(const float* __restrict__ w2, const float* __restrict__ w3,
                     float* __restrict__ w2T, float* __restrict__ w3T) {
    int i = blockIdx.x * 256 + threadIdx.x;
    if (i < 9 * 32 * 64) {
        int o = i & 63; int c = (i >> 6) & 31; int p = i >> 11;
        w2T[i] = w2[(o * 32 + c) * 9 + p];
    }
    if (i < 9 * 64 * 128) {
        int o = i & 127; int c = (i >> 7) & 63; int p = i >> 13;
        w3T[i] = w3[(o * 64 + c) * 9 + p];
    }
}

// ---------------- transpose wf4a [512][8192] -> wT4a [8192][512], 64x64 LDS tiles
__global__ void k_wT4a(const float* __restrict__ w, float* __restrict__ wT) {
    __shared__ float tile[64][65];
    int ft = blockIdx.x & 127;   // f tile
    int ot = blockIdx.x >> 7;    // o tile (0..7)
    int j = threadIdx.x & 63;
    int i0 = threadIdx.x >> 6;   // 0..3
    for (int i = i0; i < 64; i += 4)
        tile[i][j] = w[(size_t)(ot * 64 + i) * 8192 + ft * 64 + j];
    __syncthreads();
    for (int i = i0; i < 64; i += 4)
        wT[(size_t)(ft * 64 + i) * 512 + ot * 64 + j] = tile[j][i];
}

// ---------------- SC2: sparse 3x3 conv (32c -> 64o) + psp + spike -> sc2m ulong (bit o)
// 256 blocks x 1024 threads (16 waves): task = b*1024+pix. LDS 72KB -> 2 blocks/CU (full occ).
__global__ __launch_bounds__(1024) void k_sc2(const unsigned* __restrict__ s2m,
                                              const float* __restrict__ w2T,
                                              ull* __restrict__ sc2m) {
    extern __shared__ float wl[];
    for (int i = threadIdx.x; i < 9 * 32 * 64; i += 1024) wl[i] = w2T[i];
    __syncthreads();
    int task = blockIdx.x * 16 + (threadIdx.x >> 6);   // 0..4095
    int pix = task & 1023;
    int b = task >> 10;
    int h = pix >> 5, w = pix & 31;
    int lane = threadIdx.x & 63;   // o
    float y1 = 0, y2 = 0, xp = 0, r1 = 0, r2 = 0, sp = 0;
    for (int t = 0; t < 100; ++t) {
        const unsigned* mb = s2m + (size_t)(t * 4 + b) * 1024;
        float acc = 0.0f;
#pragma unroll
        for (int kh = 0; kh < 3; ++kh) {
            int ih = h - 1 + kh;
            if (ih < 0 || ih >= 32) continue;
#pragma unroll
            for (int kw = 0; kw < 3; ++kw) {
                int iw = w - 1 + kw;
                if (iw < 0 || iw >= 32) continue;
                unsigned m = __builtin_amdgcn_readfirstlane(mb[ih * 32 + iw]);
                sparse_acc64(acc, (ull)m, wl + (kh * 3 + kw) * 32 * 64, lane);
            }
        }
        float s = iir_spike_step(acc, y1, y2, xp, r1, r2, sp);
        ull mm = __ballot(s > 0.5f);
        if (lane == 0) sc2m[(size_t)(t * 4 + b) * 1024 + pix] = mm;
    }
}

// ---------------- SP2: pool SC2 masks -> s3m [t][b][16][16] ulong (bit c of 64)
__global__ void k_sp2(const ull* __restrict__ sc2m, ull* __restrict__ s3m) {
    int wid = (blockIdx.x * 256 + threadIdx.x) >> 6;   // (b*16+ho)*16+wo
    int lane = threadIdx.x & 63;                        // c
    int wo = wid & 15;
    int ho = (wid >> 4) & 15;
    int b = wid >> 8;
    float y1 = 0, y2 = 0, xp = 0, r1 = 0, r2 = 0, sp = 0;
    for (int t = 0; t < 100; ++t) {
        const ull* mb = sc2m + (size_t)(t * 4 + b) * 1024 + (2 * ho) * 32 + 2 * wo;
        ull a0 = mb[0], a1 = mb[1], a2 = mb[32], a3 = mb[33];
        float cnt = (float)(((a0 >> lane) & 1) + ((a1 >> lane) & 1) +
                            ((a2 >> lane) & 1) + ((a3 >> lane) & 1));
        float s = iir_spike_step(11.0f * cnt, y1, y2, xp, r1, r2, sp);
        ull mm = __ballot(s > 0.5f);
        if (lane == 0) s3m[(size_t)(t * 4 + b) * 256 + ho * 16 + wo] = mm;
    }
}

// ---------------- SC3: sparse 3x3 conv (64c -> 128o, o-half per block) -> s4m [..][pix][2]
// 256 blocks x 512 threads (8 waves): block = (b, pixgroup, half). LDS 144KB, 1 block/CU.
__global__ __launch_bounds__(512) void k_sc3(const ull* __restrict__ s3m,
                                             const float* __restrict__ w3T,
                                             ull* __restrict__ s4m) {
    extern __shared__ float wl[];
    int half = blockIdx.x & 1;
    int rest = blockIdx.x >> 1;          // 0..127 = b*32 + pg
    int pg = rest & 31;
    int b = rest >> 5;
    for (int i = threadIdx.x; i < 9 * 64 * 64; i += 512) {
        int o = i & 63; int pc = i >> 6;               // pc = p*64+c
        wl[i] = w3T[pc * 128 + half * 64 + o];
    }
    __syncthreads();
    int pix = pg * 8 + (threadIdx.x >> 6);
    int h = pix >> 4, w = pix & 15;
    int lane = threadIdx.x & 63;   // o within half
    float y1 = 0, y2 = 0, xp = 0, r1 = 0, r2 = 0, sp = 0;
    for (int t = 0; t < 100; ++t) {
        const ull* mb = s3m + (size_t)(t * 4 + b) * 256;
        float acc = 0.0f;
#pragma unroll
        for (int kh = 0; kh < 3; ++kh) {
            int ih = h - 1 + kh;
            if (ih < 0 || ih >= 16) continue;
#pragma unroll
            for (int kw = 0; kw < 3; ++kw) {
                int iw = w - 1 + kw;
                if (iw < 0 || iw >= 16) continue;
                ull mm64 = mb[ih * 16 + iw];
                unsigned lo = __builtin_amdgcn_readfirstlane((unsigned)mm64);
                unsigned hi = __builtin_amdgcn_readfirstlane((unsigned)(mm64 >> 32));
                ull m = ((ull)hi << 32) | lo;
                sparse_acc64(acc, m, wl + (kh * 3 + kw) * 64 * 64, lane);
            }
        }
        float s = iir_spike_step(acc, y1, y2, xp, r1, r2, sp);
        ull mm = __ballot(s > 0.5f);
        if (lane == 0) s4m[((size_t)(t * 4 + b) * 256 + pix) * 2 + half] = mm;
    }
}

// ---------------- SP3: pool SC3 masks -> pix-packed masks s5m [t][b][c=128] ulong (bit pix)
__global__ void k_sp3(const ull* __restrict__ s4m, ull* __restrict__ s5m) {
    int wid = (blockIdx.x * 256 + threadIdx.x) >> 6;   // b*128 + c
    int lane = threadIdx.x & 63;
    int c = wid & 127;
    int b = wid >> 7;
    int half = c >> 6;
    int cbit = c & 63;
    int ho = lane >> 3, wo = lane & 7;
    float y1 = 0, y2 = 0, xp = 0, r1 = 0, r2 = 0, sp = 0;
    for (int t = 0; t < 100; ++t) {
        const ull* mb = s4m + ((size_t)(t * 4 + b) * 256 + (2 * ho) * 16 + 2 * wo) * 2 + half;
        // input pixels: (2ho,2wo)=+0, (2ho,2wo+1)=+2, (2ho+1,2wo)=+32, (2ho+1,2wo+1)=+34
        ull a0 = mb[0], a1 = mb[2], a2 = mb[32], a3 = mb[34];
        float cnt = (float)(((a0 >> cbit) & 1) + ((a1 >> cbit) & 1) +
                            ((a2 >> cbit) & 1) + ((a3 >> cbit) & 1));
        float s = iir_spike_step(11.0f * cnt, y1, y2, xp, r1, r2, sp);
        ull mm = __ballot(s > 0.5f);
        if (lane == 0) s5m[(size_t)(t * 4 + b) * 128 + c] = mm;
    }
}

// ---------------- SF4a GEMM: acc[tb][512] = sum over active f of wT[f][o], batched walk
__global__ void k_gemm4a(const ull* __restrict__ s5m,
                         const float* __restrict__ wT,
                         float* __restrict__ acc_out) {
    int wg = blockIdx.x * 4 + (threadIdx.x >> 6);   // 3200 waves
    int lane = threadIdx.x & 63;
    int ot = wg & 7;
    int tb = wg >> 3;                               // 0..399
    const ull* mp = s5m + (size_t)tb * 128;
    const float* wbase = wT + ot * 64 + lane;
    float acc = 0.0f;
    for (int c = 0; c < 128; ++c) {
        ull mv = mp[c];
        unsigned lo = __builtin_amdgcn_readfirstlane((unsigned)mv);
        unsigned hi = __builtin_amdgcn_readfirstlane((unsigned)(mv >> 32));
        ull m = ((ull)hi << 32) | lo;
        const float* wb = wbase + (size_t)(c * 64) * 512;
        while (m) {
            ull m1 = m & (m - 1);
            ull m2 = m1 & (m1 - 1);
            ull m3 = m2 & (m2 - 1);
            if (m3) {
                int c0 = __builtin_ctzll(m);
                int c1 = __builtin_ctzll(m1);
                int c2 = __builtin_ctzll(m2);
                int c3 = __builtin_ctzll(m3);
                float w0 = wb[(size_t)c0 * 512];
                float w1 = wb[(size_t)c1 * 512];
                float w2 = wb[(size_t)c2 * 512];
                float w3 = wb[(size_t)c3 * 512];
                acc += w0; acc += w1; acc += w2; acc += w3;
                m = m3 & (m3 - 1);
            } else {
                acc += wb[(size_t)__builtin_ctzll(m) * 512];
                m = m1;
            }
        }
    }
    acc_out[(size_t)tb * 512 + ot * 64 + lane] = acc;
}

// ---------------- SF4a IIR: per-(b,o) scan over precomputed acc -> u8 spikes s6 [t][b][512]
__global__ void k_iir4a(const float* __restrict__ accbuf, unsigned char* __restrict__ s6) {
    int id = blockIdx.x * 64 + threadIdx.x;   // 2048 = b*512+o
    int b = id >> 9, o = id & 511;
    float y1 = 0, y2 = 0, xp = 0, r1 = 0, r2 = 0, sp = 0;
    for (int t = 0; t < 100; ++t) {
        float a = accbuf[(size_t)(t * 4 + b) * 512 + o];
        float s = iir_spike_step(a, y1, y2, xp, r1, r2, sp);
        s6[(size_t)(t * 4 + b) * 512 + o] = (unsigned char)s;
    }
}

// ---------------- SF4b: dense 512->11 -> final out [B][11][T] f32
__global__ void k_dense4b(const unsigned char* __restrict__ in,
                          const float* __restrict__ wt,
                          float* __restrict__ out) {
    int wid = blockIdx.x;      // 44 = (b,o)
    int lane = threadIdx.x;
    int o = wid % 11;
    int b = wid / 11;
    float wreg[8];
    const float* wp = wt + o * 512 + lane * 8;
#pragma unroll
    for (int k = 0; k < 8; ++k) wreg[k] = wp[k];
    float y1 = 0, y2 = 0, xp = 0, r1 = 0, r2 = 0, sp = 0;
    for (int t = 0; t < 100; ++t) {
        const unsigned char* ip = in + (size_t)(t * 4 + b) * 512 + lane * 8;
        uchar4 a = *(const uchar4*)ip;
        uchar4 c = *(const uchar4*)(ip + 4);
        float acc = wreg[0] * (float)a.x + wreg[1] * (float)a.y +
                    wreg[2] * (float)a.z + wreg[3] * (float)a.w +
                    wreg[4] * (float)c.x + wreg[5] * (float)c.y +
                    wreg[6] * (float)c.z + wreg[7] * (float)c.w;
#pragma unroll
        for (int off = 32; off > 0; off >>= 1) acc += __shfl_xor(acc, off, 64);
        float s = iir_spike_step(acc, y1, y2, xp, r1, r2, sp);
        if (lane == 0) out[(b * 11 + o) * 100 + t] = s;
    }
}

extern "C" void kernel_launch(void* const* d_in, const int* in_sizes, int n_in,
                              void* d_out, int out_size, void* d_ws, size_t ws_size,
                              hipStream_t stream) {
    const float* s_in = (const float*)d_in[0];
    const float* w1   = (const float*)d_in[1];
    const float* w2   = (const float*)d_in[2];
    const float* w3   = (const float*)d_in[3];
    const float* w4a  = (const float*)d_in[4];
    const float* w4b  = (const float*)d_in[5];
    float* out = (float*)d_out;

    char* ws = (char*)d_ws;
    ull*           s0m  = (ull*)(ws + 0);              //   409,600
    ull*           s1m  = (ull*)(ws + 409600);         // 6,553,600
    unsigned*      s2m  = (unsigned*)(ws + 6963200);   // 1,638,400
    ull*           sc2m = (ull*)(ws + 8601600);        // 3,276,800
    ull*           s3m  = (ull*)(ws + 11878400);       //   819,200
    ull*           s4m  = (ull*)(ws + 12697600);       // 1,638,400
    ull*           s5m  = (ull*)(ws + 14336000);       //   409,600
    unsigned char* s6   = (unsigned char*)(ws + 14745600);  //   204,800
    float*         accA = (float*)(ws + 14950400);     //   819,200
    float*         w2T  = (float*)(ws + 15769600);     //    73,728
    float*         w3T  = (float*)(ws + 15843328);     //   294,912
    float*         wT4a = (float*)(ws + 16138240);     // 16,777,216  (end ~32.9MB)

    // allow >64KB dynamic LDS for the sparse conv kernels
    hipFuncSetAttribute((const void*)k_sc2, hipFuncAttributeMaxDynamicSharedMemorySize, 73728);
    hipFuncSetAttribute((const void*)k_sc3, hipFuncAttributeMaxDynamicSharedMemorySize, 147456);

    k_wT<<<288, 256, 0, stream>>>(w2, w3, w2T, w3T);
    k_wT4a<<<1024, 256, 0, stream>>>(w4a, wT4a);
    k_sp0<<<128, 256, 0, stream>>>(s_in, s0m);
    k_sc1<<<2048, 256, 0, stream>>>(s0m, w1, s1m);
    k_sp1<<<512, 256, 0, stream>>>(s1m, s2m);
    k_sc2<<<256, 1024, 73728, stream>>>(s2m, w2T, sc2m);
    k_sp2<<<256, 256, 0, stream>>>(sc2m, s3m);
    k_sc3<<<256, 512, 147456, stream>>>(s3m, w3T, s4m);
    k_sp3<<<128, 256, 0, stream>>>(s4m, s5m);
    k_gemm4a<<<800, 256, 0, stream>>>(s5m, wT4a, accA);
    k_iir4a<<<32, 64, 0, stream>>>(accA, s6);
    k_dense4b<<<44, 64, 0, stream>>>(s6, w4b, out);
}